// Round 9
// baseline (273.623 us; speedup 1.0000x reference)
//
#include <hip/hip_runtime.h>

typedef unsigned short u16;
typedef unsigned int   u32;
typedef __bf16  bf16x8 __attribute__((ext_vector_type(8)));
typedef float   f32x16 __attribute__((ext_vector_type(16)));

#define CAP      16384
// Fragment-linear weight images: each 64-row quarter is stored as a sequence of
// fragments; fragment f = 64 contiguous 16B lane-chunks (1024 B). Read addr =
// lane*16 + f*1024 -> canonical conflict-free ds_read_b128, zero addr VALU.
#define L0Q_ELS  3072                     // L0 quarter: 6 frags x 512 els (k=0..47 only)
#define L0_ELS   (4*L0Q_ELS)              // 12288
#define HID_ELS  (256*256)                // 4 quarters x 32 frags x 512
#define OUT_ELS  (16*512)                 // 16 frags (i=0, t=0..15)
#define HEAD_WS  (L0_ELS + 3*HID_ELS + OUT_ELS)   // 217088 bf16 elements per head
#define HID_OFF  L0_ELS
#define OUT_OFF  (L0_ELS + 3*HID_ELS)
#define HEAD_CH  (HEAD_WS/8)              // 27136 16B-chunks per head image

union F8 { u32 u[4]; bf16x8 v; };

__device__ __forceinline__ u16 f2b(float f) {   // fp32 -> bf16 RTNE
  u32 u = __float_as_uint(f); u += 0x7fffu + ((u >> 16) & 1u); return (u16)(u >> 16);
}
__device__ __forceinline__ u32 packbf2(float a, float b) {  // bf16(a) | bf16(b)<<16
  u32 ua = __float_as_uint(a); ua += 0x7fffu + ((ua >> 16) & 1u);
  u32 ub = __float_as_uint(b); ub += 0x7fffu + ((ub >> 16) & 1u);
  return (ua >> 16) | (ub & 0xffff0000u);
}

__device__ __forceinline__ f32x16 mfma16(bf16x8 a, bf16x8 b, f32x16 c) {
  return __builtin_amdgcn_mfma_f32_32x32x16_bf16(a, b, c, 0, 0, 0);
}

// ---- async staging: global_load_lds width 16. 128 threads -> 2 KB per sweep. ----
__device__ __forceinline__ void stage_async(const u16* __restrict__ g, short* l,
                                            int bytes, int tid) {
  for (int base = tid * 16; base < bytes; base += 2048)
    __builtin_amdgcn_global_load_lds(
        (const __attribute__((address_space(1))) u32*)((const char*)g + base),
        (__attribute__((address_space(3))) u32*)((char*)l + base), 16, 0, 0);
}

// A-fragment readers: fragment-linear, conflict-free, immediate-offset addressing.
__device__ __forceinline__ bf16x8 fragL0(const short* sl, int i, int t, int lane) {
  return *(const bf16x8*)((const char*)sl + ((i*3 + t) << 10) + (lane << 4));
}
__device__ __forceinline__ bf16x8 fragH(const short* sl, int i, int t, int lane) {
  return *(const bf16x8*)((const char*)sl + ((i*16 + t) << 10) + (lane << 4));
}

__device__ __forceinline__ void load_bias_raw(const float* b, int r, int hh, float4 o[4]) {
#pragma unroll
  for (int g = 0; g < 4; ++g) o[g] = *(const float4*)(b + 32*r + 8*g + 4*hh);
}

// D(f32x16, C-layout) -> relu -> bf16 -> B-layout tiles via lane^32 exchange
__device__ __forceinline__ void epilogue(f32x16 c, int hh, F8& t0, F8& t1) {
  u32 P[8];
#pragma unroll
  for (int i = 0; i < 8; ++i)
    P[i] = packbf2(fmaxf(c[2*i], 0.f), fmaxf(c[2*i+1], 0.f));
  u32 s0 = hh ? P[0] : P[2], s1 = hh ? P[1] : P[3];
  u32 s2 = hh ? P[4] : P[6], s3 = hh ? P[5] : P[7];
  u32 x0 = __shfl_xor(s0, 32, 64), x1 = __shfl_xor(s1, 32, 64);
  u32 x2 = __shfl_xor(s2, 32, 64), x3 = __shfl_xor(s3, 32, 64);
  t0.u[0] = hh ? x0 : P[0]; t0.u[1] = hh ? x1 : P[1];
  t0.u[2] = hh ? P[2] : x0; t0.u[3] = hh ? P[3] : x1;
  t1.u[0] = hh ? x2 : P[4]; t1.u[1] = hh ? x3 : P[5];
  t1.u[2] = hh ? P[6] : x2; t1.u[3] = hh ? P[7] : x3;
}
// bias-adding variant (acc zero-init; bias lands pre-relu). bb = this acc's 32 rows.
__device__ __forceinline__ void epilogue_b(f32x16 c, const float4 bb[4], int hh, F8& t0, F8& t1) {
  u32 P[8];
  P[0] = packbf2(fmaxf(c[0]  + bb[0].x, 0.f), fmaxf(c[1]  + bb[0].y, 0.f));
  P[1] = packbf2(fmaxf(c[2]  + bb[0].z, 0.f), fmaxf(c[3]  + bb[0].w, 0.f));
  P[2] = packbf2(fmaxf(c[4]  + bb[1].x, 0.f), fmaxf(c[5]  + bb[1].y, 0.f));
  P[3] = packbf2(fmaxf(c[6]  + bb[1].z, 0.f), fmaxf(c[7]  + bb[1].w, 0.f));
  P[4] = packbf2(fmaxf(c[8]  + bb[2].x, 0.f), fmaxf(c[9]  + bb[2].y, 0.f));
  P[5] = packbf2(fmaxf(c[10] + bb[2].z, 0.f), fmaxf(c[11] + bb[2].w, 0.f));
  P[6] = packbf2(fmaxf(c[12] + bb[3].x, 0.f), fmaxf(c[13] + bb[3].y, 0.f));
  P[7] = packbf2(fmaxf(c[14] + bb[3].z, 0.f), fmaxf(c[15] + bb[3].w, 0.f));
  u32 s0 = hh ? P[0] : P[2], s1 = hh ? P[1] : P[3];
  u32 s2 = hh ? P[4] : P[6], s3 = hh ? P[5] : P[7];
  u32 x0 = __shfl_xor(s0, 32, 64), x1 = __shfl_xor(s1, 32, 64);
  u32 x2 = __shfl_xor(s2, 32, 64), x3 = __shfl_xor(s3, 32, 64);
  t0.u[0] = hh ? x0 : P[0]; t0.u[1] = hh ? x1 : P[1];
  t0.u[2] = hh ? P[2] : x0; t0.u[3] = hh ? P[3] : x1;
  t1.u[0] = hh ? x2 : P[4]; t1.u[1] = hh ? x3 : P[5];
  t1.u[2] = hh ? P[6] : x2; t1.u[3] = hh ? P[7] : x3;
}

// ---------------- prep: shallow, output-indexed, write-coalesced (R8, unchanged) ----------------
__global__ void prep(const float* __restrict__ W_in, const float* __restrict__ b_in,
                     const float* __restrict__ W_hid, const float* __restrict__ W_out,
                     u16* __restrict__ ws,
                     const uint4* __restrict__ csrc, uint4* __restrict__ cdst) {
  const int b = blockIdx.x, tid = threadIdx.x;
  if (b >= 1696) {                                  // coords passthrough (2 MB)
    const int i = (b - 1696) * 256 + tid;
    cdst[i] = csrc[i];
    return;
  }
  const int ct = b * 256 + tid;                     // global chunk id, 434176 total
  const int head = ct / HEAD_CH;
  const int r = ct - head * HEAD_CH;                // chunk within head image
  u16 v[8];
  if (r < 1536) {                                   // L0: 4 quarters x 6 frags
    const int Q = r / 384, rr = r - Q * 384;
    const int f = rr >> 6, ll = rr & 63;
    const int i = (f >= 3) ? 1 : 0, t = f - 3 * i;
    const int hh = ll >> 5, n2 = ll & 31;
    const int kb = 8 * (2 * t + hh), nn = Q * 64 + i * 32 + n2;
#pragma unroll
    for (int j = 0; j < 8; ++j) {
      const int k = kb + j;
      v[j] = (k < 40) ? f2b(W_in[head * 10240 + k * 256 + nn])
           : (k == 40) ? f2b(b_in[head * 256 + nn]) : (u16)0;
    }
  } else if (r < 26112) {                           // hidden: 3 layers x 4 quarters x 32 frags
    const int r2 = r - 1536;
    const int l = r2 >> 13, q2 = r2 & 8191;
    const int Q = q2 >> 11, rr = q2 & 2047;
    const int f = rr >> 6, ll = rr & 63;
    const int i = f >> 4, t = f & 15;
    const int hh = ll >> 5, n2 = ll & 31;
    const int kb = 8 * (2 * t + hh), nn = Q * 64 + i * 32 + n2;
    const float* src = W_hid + head * 196608 + l * 65536 + nn;
#pragma unroll
    for (int j = 0; j < 8; ++j)
      v[j] = f2b(src[(kb + j) * 256]);
  } else {                                          // out: 16 frags, rows>=3 zero
    const int r3 = r - 26112;
    const int t = r3 >> 6, ll = r3 & 63;
    const int hh = ll >> 5, n2 = ll & 31;
    const int kb = 8 * (2 * t + hh);
#pragma unroll
    for (int j = 0; j < 8; ++j)
      v[j] = (n2 < 3) ? f2b(W_out[head * 768 + (kb + j) * 3 + n2]) : (u16)0;
  }
  uint4 o;
  o.x = (u32)v[0] | ((u32)v[1] << 16); o.y = (u32)v[2] | ((u32)v[3] << 16);
  o.z = (u32)v[4] | ((u32)v[5] << 16); o.w = (u32)v[6] | ((u32)v[7] << 16);
  *(uint4*)(ws + (long)ct * 8) = o;
}

// ---------------- main fused MLP v2: 64 points/wave, 1 wave/SIMD ----------------
// 128 threads (2 waves) x 128 points; 2 blocks/CU (LDS 64KB each). Each wave owns
// TWO 32-pt B-tiles: every A-fragment read feeds 4 independent MFMAs (2x LDS-read
// reuse, 4-wide MFMA ILP). 1 wave/SIMD unlocks the 512-VGPR budget (~80 spare
// regs for compiler read-prefetch). Staging/fragment layout/epilogue math as R6-R8.
__launch_bounds__(128, 1)
__global__ void mlp_main(const float* __restrict__ coords, const int* __restrict__ head_idx,
                         const float* __restrict__ b_hid, const float* __restrict__ b_out,
                         const u16* __restrict__ ws, float* __restrict__ out) {
  __shared__ short ring[2 * 16384];                  // 2 x 32 KB weight-quarter slots
  const int tid = threadIdx.x;
  const int lane = tid & 63, wv = tid >> 6;          // wv 0..1
  const int n = lane & 31, hh = lane >> 5;
  const int head = blockIdx.x & 15, chunk = blockIdx.x >> 4;   // head%16 -> fixed XCD
  const u16* wsh = ws + head * HEAD_WS;

  // stage L0 quarters 0,1 into slots 0,1 (async; drained by barrier below)
  stage_async(wsh + 0*L0Q_ELS, ring,          6144, tid);
  stage_async(wsh + 1*L0Q_ELS, ring + 16384,  6144, tid);

  // gather two point-tiles per wave
  const int pt = chunk*128 + wv*64 + n;              // tile-lo point
  const int g0 = head_idx[head*CAP + pt];
  const int g1 = head_idx[head*CAP + pt + 32];       // tile-hi point
  const float2 c0 = *(const float2*)(coords + 2*g0);
  const float2 c1 = *(const float2*)(coords + 2*g1);
  const float bo0 = b_out[head*3+0], bo1 = b_out[head*3+1], bo2 = b_out[head*3+2];

  // positional encoding (B-layout: lane = point, k = 16t + 8*hh + j)
  auto build_pe = [&](float xs, float ys, F8 (&pe)[3]) {
#pragma unroll
    for (int t = 0; t < 3; ++t) {
      float e[8];
#pragma unroll
      for (int half = 0; half < 2; ++half) {
        const int l = 4*t + 2*hh + half;             // k = 4l + comp
        if (l < 10) {
          const float fr = 3.14159265358979323846f * (float)(1 << l);
          float s1, cc1, s2, cc2;
          sincosf(xs * fr, &s1, &cc1);
          sincosf(ys * fr, &s2, &cc2);
          e[4*half+0] = s1; e[4*half+1] = s2; e[4*half+2] = cc1; e[4*half+3] = cc2;
        } else {                                      // k=40 -> 1.0 (folded bias), pad 0
          e[4*half+0] = (l == 10) ? 1.0f : 0.0f;
          e[4*half+1] = 0.f; e[4*half+2] = 0.f; e[4*half+3] = 0.f;
        }
      }
      pe[t].u[0] = packbf2(e[0], e[1]); pe[t].u[1] = packbf2(e[2], e[3]);
      pe[t].u[2] = packbf2(e[4], e[5]); pe[t].u[3] = packbf2(e[6], e[7]);
    }
  };
  F8 peA[3], peB[3];
  build_pe(c0.x, c0.y, peA);
  build_pe(c1.x, c1.y, peB);

  F8 s0a[16], s0b[16], s1a[16], s1b[16];             // ping-pong act sets, lo/hi tiles
  __syncthreads();                                   // L0 q0/q1 staged

  // ===== layer 0: pe -> set0 (K=48, bias folded into weights) =====
#pragma unroll
  for (int rp = 0; rp < 4; ++rp) {
    short* sl = ring + (rp & 1) * 16384;
    f32x16 a00 = (f32x16)0.f, a01 = (f32x16)0.f, a10 = (f32x16)0.f, a11 = (f32x16)0.f;
    __builtin_amdgcn_s_setprio(1);
#pragma unroll
    for (int t = 0; t < 3; ++t) {
      bf16x8 w0 = fragL0(sl, 0, t, lane);
      bf16x8 w1 = fragL0(sl, 1, t, lane);
      a00 = mfma16(w0, peA[t].v, a00);
      a01 = mfma16(w0, peB[t].v, a01);
      a10 = mfma16(w1, peA[t].v, a10);
      a11 = mfma16(w1, peB[t].v, a11);
    }
    __builtin_amdgcn_s_setprio(0);
    __syncthreads();                                 // all waves done reading this slot
    const u16* src = (rp < 2) ? (wsh + (rp + 2)*L0Q_ELS) : (wsh + HID_OFF + (rp - 2)*16384);
    const int bytes = (rp < 2) ? 6144 : 32768;
    stage_async(src, sl, bytes, tid);                // fire-and-forget; drained at next barrier
    epilogue(a00, hh, s0a[4*rp+0], s0a[4*rp+1]);
    epilogue(a10, hh, s0a[4*rp+2], s0a[4*rp+3]);
    epilogue(a01, hh, s0b[4*rp+0], s0b[4*rp+1]);
    epilogue(a11, hh, s0b[4*rp+2], s0b[4*rp+3]);
  }

  // ===== hidden layers =====
  auto hid_layer = [&](const float* bias, F8 (&ina)[16], F8 (&inb)[16],
                       F8 (&outa)[16], F8 (&outb)[16],
                       const u16* j0, const u16* j1, const u16* j2, const u16* j3,
                       int b2, int b3) {
    const u16* jsrc[4] = { j0, j1, j2, j3 };
    const int  jb[4]   = { 32768, 32768, b2, b3 };
#pragma unroll
    for (int rp = 0; rp < 4; ++rp) {
      short* sl = ring + (rp & 1) * 16384;
      float4 br0[4], br1[4];                         // issued early, consumed in epilogue
      load_bias_raw(bias, 2*rp+0, hh, br0);
      load_bias_raw(bias, 2*rp+1, hh, br1);
      f32x16 a00 = (f32x16)0.f, a01 = (f32x16)0.f, a10 = (f32x16)0.f, a11 = (f32x16)0.f;
      __builtin_amdgcn_s_setprio(1);
#pragma unroll
      for (int t = 0; t < 16; ++t) {
        bf16x8 w0 = fragH(sl, 0, t, lane);
        bf16x8 w1 = fragH(sl, 1, t, lane);
        a00 = mfma16(w0, ina[t].v, a00);
        a01 = mfma16(w0, inb[t].v, a01);
        a10 = mfma16(w1, ina[t].v, a10);
        a11 = mfma16(w1, inb[t].v, a11);
      }
      __builtin_amdgcn_s_setprio(0);
      __syncthreads();                                // all waves done with this quarter
      if (jb[rp] > 0) stage_async(jsrc[rp], sl, jb[rp], tid);  // refill freed slot
      epilogue_b(a00, br0, hh, outa[4*rp+0], outa[4*rp+1]);
      epilogue_b(a10, br1, hh, outa[4*rp+2], outa[4*rp+3]);
      epilogue_b(a01, br0, hh, outb[4*rp+0], outb[4*rp+1]);
      epilogue_b(a11, br1, hh, outb[4*rp+2], outb[4*rp+3]);
    }
  };

  const u16* hb = wsh + HID_OFF;
  hid_layer(b_hid + (head*3+0)*256, s0a, s0b, s1a, s1b,
            hb + 2*16384, hb + 3*16384, hb + HID_ELS, hb + HID_ELS + 16384, 32768, 32768);
  hid_layer(b_hid + (head*3+1)*256, s1a, s1b, s0a, s0b,
            hb + HID_ELS + 2*16384, hb + HID_ELS + 3*16384,
            hb + 2*HID_ELS, hb + 2*HID_ELS + 16384, 32768, 32768);
  hid_layer(b_hid + (head*3+2)*256, s0a, s0b, s1a, s1b,
            hb + 2*HID_ELS + 2*16384, hb + 2*HID_ELS + 3*16384,
            wsh + OUT_OFF, (const u16*)0, 16384, 0);

  // ===== out layer: set1 x W_out^T (16-frag image in slot 0), scatter both tiles =====
  f32x16 o0 = (f32x16)0.f, o1 = (f32x16)0.f;
  __builtin_amdgcn_s_setprio(1);
#pragma unroll
  for (int t = 0; t < 16; ++t) {
    bf16x8 w = fragH(ring, 0, t, lane);
    o0 = mfma16(w, s1a[t].v, o0);
    o1 = mfma16(w, s1b[t].v, o1);
  }
  __builtin_amdgcn_s_setprio(0);
  if (hh == 0) {                                     // rows 0..2 live in h=0 regs 0..2
    const long b0 = (long)g0 * 3;
    out[b0 + 0] = o0[0] + bo0;
    out[b0 + 1] = o0[1] + bo1;
    out[b0 + 2] = o0[2] + bo2;
    const long b1 = (long)g1 * 3;
    out[b1 + 0] = o1[0] + bo0;
    out[b1 + 1] = o1[1] + bo1;
    out[b1 + 2] = o1[2] + bo2;
  }
}

extern "C" void kernel_launch(void* const* d_in, const int* in_sizes, int n_in,
                              void* d_out, int out_size, void* d_ws, size_t ws_size,
                              hipStream_t stream) {
  const float* coords   = (const float*)d_in[0];
  const int*   head_idx = (const int*)d_in[1];
  const float* W_in     = (const float*)d_in[2];
  const float* b_in     = (const float*)d_in[3];
  const float* W_hid    = (const float*)d_in[4];
  const float* b_hid    = (const float*)d_in[5];
  const float* W_out    = (const float*)d_in[6];
  const float* b_out    = (const float*)d_in[7];
  float* out = (float*)d_out;
  u16*   ws  = (u16*)d_ws;
  if (ws_size < (size_t)HEAD_WS * 16 * sizeof(u16)) return;  // need ~6.9 MB scratch

  // prep: 1696 image-chunk blocks + 512 coords-copy blocks (shallow, write-coalesced)
  prep<<<dim3(2208), dim3(256), 0, stream>>>(W_in, b_in, W_hid, W_out, ws,
                                             (const uint4*)coords, (uint4*)(out + 786432));
  // v2: 2048 blocks x 128 threads; 2 blocks/CU; 64 points per wave
  mlp_main<<<dim3(2048), dim3(128), 0, stream>>>(coords, head_idx, b_hid, b_out, ws, out);
}

// Round 10
// 191.854 us; speedup vs baseline: 1.4262x; 1.4262x over previous
//
#include <hip/hip_runtime.h>

typedef unsigned short u16;
typedef unsigned int   u32;
typedef __bf16  bf16x8 __attribute__((ext_vector_type(8)));
typedef float   f32x16 __attribute__((ext_vector_type(16)));

#define CAP      16384
// Fragment-linear weight images: each 64-row quarter is stored as a sequence of
// fragments; fragment f = 64 contiguous 16B lane-chunks (1024 B). Read addr =
// lane*16 + f*1024 -> canonical conflict-free ds_read_b128, zero addr VALU.
#define L0Q_ELS  3072                     // L0 quarter: 6 frags x 512 els (k=0..47 only)
#define L0_ELS   (4*L0Q_ELS)              // 12288
#define HID_ELS  (256*256)                // 4 quarters x 32 frags x 512
#define OUT_ELS  (16*512)                 // 16 frags (i=0, t=0..15)
#define HEAD_WS  (L0_ELS + 3*HID_ELS + OUT_ELS)   // 217088 bf16 elements per head
#define HID_OFF  L0_ELS
#define OUT_OFF  (L0_ELS + 3*HID_ELS)
#define HEAD_CH  (HEAD_WS/8)              // 27136 16B-chunks per head image

union F8 { u32 u[4]; bf16x8 v; };

__device__ __forceinline__ u16 f2b(float f) {   // fp32 -> bf16 RTNE
  u32 u = __float_as_uint(f); u += 0x7fffu + ((u >> 16) & 1u); return (u16)(u >> 16);
}
__device__ __forceinline__ u32 packbf2(float a, float b) {  // bf16(a) | bf16(b)<<16
  u32 ua = __float_as_uint(a); ua += 0x7fffu + ((ua >> 16) & 1u);
  u32 ub = __float_as_uint(b); ub += 0x7fffu + ((ub >> 16) & 1u);
  return (ua >> 16) | (ub & 0xffff0000u);
}
// HW packed f32->bf16 (T12/m240: no builtin on gfx950, asm only). lo=a, hi=b.
__device__ __forceinline__ u32 cvtpk(float a, float b) {
  u32 r;
  asm("v_cvt_pk_bf16_f32 %0, %1, %2" : "=v"(r) : "v"(a), "v"(b));
  return r;
}

__device__ __forceinline__ f32x16 mfma16(bf16x8 a, bf16x8 b, f32x16 c) {
  return __builtin_amdgcn_mfma_f32_32x32x16_bf16(a, b, c, 0, 0, 0);
}

// ---- async staging: global_load_lds width 16 (image already fragment-linear,
//      LDS dest is lane-linear: base + tid*16). 256 threads -> 4 KB per sweep. ----
__device__ __forceinline__ void stage_async(const u16* __restrict__ g, short* l,
                                            int bytes, int tid) {
  for (int base = tid * 16; base < bytes; base += 4096)
    __builtin_amdgcn_global_load_lds(
        (const __attribute__((address_space(1))) u32*)((const char*)g + base),
        (__attribute__((address_space(3))) u32*)((char*)l + base), 16, 0, 0);
}

// A-fragment readers: fragment-linear, conflict-free, immediate-offset addressing.
// Fragment (i,t) holds rows 32i+n, k-chunk (2t+hh), at lane = hh*32+n.
__device__ __forceinline__ bf16x8 fragL0(const short* sl, int i, int t, int lane) {
  return *(const bf16x8*)((const char*)sl + ((i*3 + t) << 10) + (lane << 4));
}
__device__ __forceinline__ bf16x8 fragH(const short* sl, int i, int t, int lane) {
  return *(const bf16x8*)((const char*)sl + ((i*16 + t) << 10) + (lane << 4));
}

__device__ __forceinline__ void load_bias_raw(const float* b, int r, int hh, float4 o[4]) {
#pragma unroll
  for (int g = 0; g < 4; ++g) o[g] = *(const float4*)(b + 32*r + 8*g + 4*hh);
}
__device__ __forceinline__ f32x16 bias_to_acc(const float4 raw[4]) {
  f32x16 a;
#pragma unroll
  for (int g = 0; g < 4; ++g) {
    a[4*g+0] = raw[g].x; a[4*g+1] = raw[g].y;
    a[4*g+2] = raw[g].z; a[4*g+3] = raw[g].w;
  }
  return a;
}

// D(f32x16, C-layout) -> relu -> bf16 (v_cvt_pk) -> B-layout tiles via lane^32 exchange
__device__ __forceinline__ void epilogue(f32x16 c, int hh, F8& t0, F8& t1) {
  u32 P[8];
#pragma unroll
  for (int i = 0; i < 8; ++i)
    P[i] = cvtpk(fmaxf(c[2*i], 0.f), fmaxf(c[2*i+1], 0.f));
  u32 s0 = hh ? P[0] : P[2], s1 = hh ? P[1] : P[3];
  u32 s2 = hh ? P[4] : P[6], s3 = hh ? P[5] : P[7];
  u32 x0 = __shfl_xor(s0, 32, 64), x1 = __shfl_xor(s1, 32, 64);
  u32 x2 = __shfl_xor(s2, 32, 64), x3 = __shfl_xor(s3, 32, 64);
  t0.u[0] = hh ? x0 : P[0]; t0.u[1] = hh ? x1 : P[1];
  t0.u[2] = hh ? P[2] : x0; t0.u[3] = hh ? P[3] : x1;
  t1.u[0] = hh ? x2 : P[4]; t1.u[1] = hh ? x3 : P[5];
  t1.u[2] = hh ? P[6] : x2; t1.u[3] = hh ? P[7] : x3;
}

// ---------------- prep: shallow, output-indexed, write-coalesced (R8, unchanged) ----------------
__global__ void prep(const float* __restrict__ W_in, const float* __restrict__ b_in,
                     const float* __restrict__ W_hid, const float* __restrict__ W_out,
                     u16* __restrict__ ws,
                     const uint4* __restrict__ csrc, uint4* __restrict__ cdst) {
  const int b = blockIdx.x, tid = threadIdx.x;
  if (b >= 1696) {                                  // coords passthrough (2 MB)
    const int i = (b - 1696) * 256 + tid;
    cdst[i] = csrc[i];
    return;
  }
  const int ct = b * 256 + tid;                     // global chunk id, 434176 total
  const int head = ct / HEAD_CH;
  const int r = ct - head * HEAD_CH;                // chunk within head image
  u16 v[8];
  if (r < 1536) {                                   // L0: 4 quarters x 6 frags
    const int Q = r / 384, rr = r - Q * 384;
    const int f = rr >> 6, ll = rr & 63;
    const int i = (f >= 3) ? 1 : 0, t = f - 3 * i;
    const int hh = ll >> 5, n2 = ll & 31;
    const int kb = 8 * (2 * t + hh), nn = Q * 64 + i * 32 + n2;
#pragma unroll
    for (int j = 0; j < 8; ++j) {
      const int k = kb + j;
      v[j] = (k < 40) ? f2b(W_in[head * 10240 + k * 256 + nn])
           : (k == 40) ? f2b(b_in[head * 256 + nn]) : (u16)0;
    }
  } else if (r < 26112) {                           // hidden: 3 layers x 4 quarters x 32 frags
    const int r2 = r - 1536;
    const int l = r2 >> 13, q2 = r2 & 8191;
    const int Q = q2 >> 11, rr = q2 & 2047;
    const int f = rr >> 6, ll = rr & 63;
    const int i = f >> 4, t = f & 15;
    const int hh = ll >> 5, n2 = ll & 31;
    const int kb = 8 * (2 * t + hh), nn = Q * 64 + i * 32 + n2;
    const float* src = W_hid + head * 196608 + l * 65536 + nn;
#pragma unroll
    for (int j = 0; j < 8; ++j)
      v[j] = f2b(src[(kb + j) * 256]);
  } else {                                          // out: 16 frags, rows>=3 zero
    const int r3 = r - 26112;
    const int t = r3 >> 6, ll = r3 & 63;
    const int hh = ll >> 5, n2 = ll & 31;
    const int kb = 8 * (2 * t + hh);
#pragma unroll
    for (int j = 0; j < 8; ++j)
      v[j] = (n2 < 3) ? f2b(W_out[head * 768 + (kb + j) * 3 + n2]) : (u16)0;
  }
  uint4 o;
  o.x = (u32)v[0] | ((u32)v[1] << 16); o.y = (u32)v[2] | ((u32)v[3] << 16);
  o.z = (u32)v[4] | ((u32)v[5] << 16); o.w = (u32)v[6] | ((u32)v[7] << 16);
  *(uint4*)(ws + (long)ct * 8) = o;
}

// ---------------- main fused MLP ----------------
// 256 threads (4 waves) x 128 points; 2 blocks/CU; 2 waves/SIMD — proven optimal
// config (R9 showed 1 wave/SIMD loses; VGPR caps 8 waves/CU; LDS caps 2 blocks).
// R7 structure restored byte-for-byte except epilogue pack: v_cvt_pk_bf16_f32.
__launch_bounds__(256, 2)
__global__ void mlp_main(const float* __restrict__ coords, const int* __restrict__ head_idx,
                         const float* __restrict__ b_hid, const float* __restrict__ b_out,
                         const u16* __restrict__ ws, float* __restrict__ out) {
  __shared__ short ring[2 * 16384];                  // 2 x 32 KB weight-quarter slots
  const int tid = threadIdx.x;
  const int lane = tid & 63, wv = tid >> 6;          // wv 0..3
  const int n = lane & 31, hh = lane >> 5;
  const int head = blockIdx.x & 15, chunk = blockIdx.x >> 4;   // head%16 -> fixed XCD (L2 locality)
  const u16* wsh = ws + head * HEAD_WS;

  // stage L0 quarters 0,1 into slots 0,1 (async; drained by barrier below)
  stage_async(wsh + 0*L0Q_ELS, ring,          6144, tid);
  stage_async(wsh + 1*L0Q_ELS, ring + 16384,  6144, tid);

  // gather + positional encoding (B-layout: lane = point, k = 16t + 8*hh + j)
  const int pt = chunk*128 + wv*32 + n;
  const int g  = head_idx[head*CAP + pt];
  const float2 cxy = *(const float2*)(coords + 2*g);
  const float xs = cxy.x, ys = cxy.y;
  const float bo0 = b_out[head*3+0], bo1 = b_out[head*3+1], bo2 = b_out[head*3+2];

  F8 pe[3];
#pragma unroll
  for (int t = 0; t < 3; ++t) {
    float e[8];
#pragma unroll
    for (int half = 0; half < 2; ++half) {
      const int l = 4*t + 2*hh + half;               // k = 4l + comp; comp: sinx,siny,cosx,cosy
      if (l < 10) {
        const float fr = 3.14159265358979323846f * (float)(1 << l);
        float s1, c1, s2, c2;
        sincosf(xs * fr, &s1, &c1);
        sincosf(ys * fr, &s2, &c2);
        e[4*half+0] = s1; e[4*half+1] = s2; e[4*half+2] = c1; e[4*half+3] = c2;
      } else {                                        // k=40 -> 1.0 (folded bias), rest pad 0
        e[4*half+0] = (l == 10) ? 1.0f : 0.0f;
        e[4*half+1] = 0.f; e[4*half+2] = 0.f; e[4*half+3] = 0.f;
      }
    }
    pe[t].u[0] = packbf2(e[0], e[1]); pe[t].u[1] = packbf2(e[2], e[3]);
    pe[t].u[2] = packbf2(e[4], e[5]); pe[t].u[3] = packbf2(e[6], e[7]);
  }

  F8 act0[16], act1[16];
  __syncthreads();                                   // L0 q0/q1 staged

  // ===== layer 0: pe -> act0 (K=48, bias folded) =====
#pragma unroll
  for (int rp = 0; rp < 4; ++rp) {
    short* sl = ring + (rp & 1) * 16384;
    f32x16 acc0 = (f32x16)0.f, acc1 = (f32x16)0.f;
    __builtin_amdgcn_s_setprio(1);
#pragma unroll
    for (int t = 0; t < 3; ++t) {
      acc0 = mfma16(fragL0(sl, 0, t, lane), pe[t].v, acc0);
      acc1 = mfma16(fragL0(sl, 1, t, lane), pe[t].v, acc1);
    }
    __builtin_amdgcn_s_setprio(0);
    __syncthreads();                                 // all waves done reading this slot
    const u16* src = (rp < 2) ? (wsh + (rp + 2)*L0Q_ELS) : (wsh + HID_OFF + (rp - 2)*16384);
    const int bytes = (rp < 2) ? 6144 : 32768;
    stage_async(src, sl, bytes, tid);                // fire-and-forget; drained at next barrier
    epilogue(acc0, hh, act0[4*rp+0], act0[4*rp+1]);
    epilogue(acc1, hh, act0[4*rp+2], act0[4*rp+3]);
  }

  // ===== hidden layers =====
  auto hid_layer = [&](const float* bias, F8 (&ain)[16], F8 (&aout)[16],
                       const u16* j0, const u16* j1, const u16* j2, const u16* j3,
                       int b2, int b3) {
    float4 bc0[4], bc1[4], bn0[4], bn1[4];
    load_bias_raw(bias, 0, hh, bc0); load_bias_raw(bias, 1, hh, bc1);
    const u16* jsrc[4] = { j0, j1, j2, j3 };
    const int  jb[4]   = { 32768, 32768, b2, b3 };
#pragma unroll
    for (int rp = 0; rp < 4; ++rp) {
      short* sl = ring + (rp & 1) * 16384;
      if (rp < 3) { load_bias_raw(bias, 2*rp+2, hh, bn0); load_bias_raw(bias, 2*rp+3, hh, bn1); }
      f32x16 acc0 = bias_to_acc(bc0);
      f32x16 acc1 = bias_to_acc(bc1);
      __builtin_amdgcn_s_setprio(1);
#pragma unroll
      for (int t = 0; t < 16; ++t) {
        bf16x8 a0 = fragH(sl, 0, t, lane);
        bf16x8 a1 = fragH(sl, 1, t, lane);
        acc0 = mfma16(a0, ain[t].v, acc0);
        acc1 = mfma16(a1, ain[t].v, acc1);
      }
      __builtin_amdgcn_s_setprio(0);
      __syncthreads();                                // all waves done with this quarter
      if (jb[rp] > 0) stage_async(jsrc[rp], sl, jb[rp], tid);  // refill freed slot
      epilogue(acc0, hh, aout[4*rp+0], aout[4*rp+1]);
      epilogue(acc1, hh, aout[4*rp+2], aout[4*rp+3]);
      if (rp < 3) {
#pragma unroll
        for (int q = 0; q < 4; ++q) { bc0[q] = bn0[q]; bc1[q] = bn1[q]; }
      }
    }
  };

  const u16* hb = wsh + HID_OFF;
  hid_layer(b_hid + (head*3+0)*256, act0, act1,
            hb + 2*16384, hb + 3*16384, hb + HID_ELS, hb + HID_ELS + 16384, 32768, 32768);
  hid_layer(b_hid + (head*3+1)*256, act1, act0,
            hb + HID_ELS + 2*16384, hb + HID_ELS + 3*16384,
            hb + 2*HID_ELS, hb + 2*HID_ELS + 16384, 32768, 32768);
  hid_layer(b_hid + (head*3+2)*256, act0, act1,
            hb + 2*HID_ELS + 2*16384, hb + 2*HID_ELS + 3*16384,
            wsh + OUT_OFF, (const u16*)0, 16384, 0);

  // ===== out layer: act1 x W_out^T (16-frag image in slot 0), scatter =====
  f32x16 acc = (f32x16)0.f;
  __builtin_amdgcn_s_setprio(1);
#pragma unroll
  for (int t = 0; t < 16; ++t)
    acc = mfma16(fragH(ring, 0, t, lane), act1[t].v, acc);
  __builtin_amdgcn_s_setprio(0);
  if (hh == 0) {                                     // rows 0..2 live in h=0 regs 0..2
    const long base = (long)g * 3;
    out[base + 0] = acc[0] + bo0;
    out[base + 1] = acc[1] + bo1;
    out[base + 2] = acc[2] + bo2;
  }
}

extern "C" void kernel_launch(void* const* d_in, const int* in_sizes, int n_in,
                              void* d_out, int out_size, void* d_ws, size_t ws_size,
                              hipStream_t stream) {
  const float* coords   = (const float*)d_in[0];
  const int*   head_idx = (const int*)d_in[1];
  const float* W_in     = (const float*)d_in[2];
  const float* b_in     = (const float*)d_in[3];
  const float* W_hid    = (const float*)d_in[4];
  const float* b_hid    = (const float*)d_in[5];
  const float* W_out    = (const float*)d_in[6];
  const float* b_out    = (const float*)d_in[7];
  float* out = (float*)d_out;
  u16*   ws  = (u16*)d_ws;
  if (ws_size < (size_t)HEAD_WS * 16 * sizeof(u16)) return;  // need ~6.9 MB scratch

  // prep: 1696 image-chunk blocks + 512 coords-copy blocks (shallow, write-coalesced)
  prep<<<dim3(2208), dim3(256), 0, stream>>>(W_in, b_in, W_hid, W_out, ws,
                                             (const uint4*)coords, (uint4*)(out + 786432));
  mlp_main<<<dim3(2048), dim3(256), 0, stream>>>(coords, head_idx, b_hid, b_out, ws, out);
}